// Round 1
// 279.717 us; speedup vs baseline: 1.0294x; 1.0294x over previous
//
#include <hip/hip_runtime.h>
#include <hip/hip_bf16.h>

#define T_ 1024
#define H_ 1024
#define I_ 512
#define IS_ 2048
#define E_ 16

typedef __attribute__((ext_vector_type(8))) short short8;
typedef __attribute__((ext_vector_type(4))) float f32x4;

__device__ __forceinline__ unsigned short f2bf(float f) {
  unsigned u = __builtin_bit_cast(unsigned, f);
  unsigned r = (u + 0x7fffu + ((u >> 16) & 1u)) >> 16;
  return (unsigned short)r;
}

__device__ __forceinline__ void gload16(const void* g, void* l) {
  __builtin_amdgcn_global_load_lds(
      (const __attribute__((address_space(1))) unsigned int*)g,
      (__attribute__((address_space(3))) unsigned int*)l, 16, 0, 0);
}

// ------------- transpose tile body: src fp32 [b][R][C] -> dst bf16 [b][C][R] -------------
__device__ __forceinline__ void transpose_tile(
    const float* __restrict__ src, unsigned short* __restrict__ dst,
    int C, int dld, long sbs, long dbs, int bx, int by, int bz) {
  __shared__ unsigned short tile[64 * 72];
  const float* s = src + (long)bz * sbs + ((long)by * 64) * C + bx * 64;
  int cgrp = threadIdx.x & 15, rgrp = threadIdx.x >> 4;
  int c = cgrp << 2, r0 = rgrp << 2;
  const float* sp = s + (long)r0 * C + c;
  float4 v0 = *(const float4*)(sp);
  float4 v1 = *(const float4*)(sp + C);
  float4 v2 = *(const float4*)(sp + 2 * C);
  float4 v3 = *(const float4*)(sp + 3 * C);
  ushort4 w;
  w = (ushort4){f2bf(v0.x), f2bf(v1.x), f2bf(v2.x), f2bf(v3.x)};
  *(ushort4*)&tile[(c + 0) * 72 + r0] = w;
  w = (ushort4){f2bf(v0.y), f2bf(v1.y), f2bf(v2.y), f2bf(v3.y)};
  *(ushort4*)&tile[(c + 1) * 72 + r0] = w;
  w = (ushort4){f2bf(v0.z), f2bf(v1.z), f2bf(v2.z), f2bf(v3.z)};
  *(ushort4*)&tile[(c + 2) * 72 + r0] = w;
  w = (ushort4){f2bf(v0.w), f2bf(v1.w), f2bf(v2.w), f2bf(v3.w)};
  *(ushort4*)&tile[(c + 3) * 72 + r0] = w;
  __syncthreads();
  int orr = threadIdx.x >> 2;
  int ks = (threadIdx.x & 3) << 4;
  uint4 o0 = *(const uint4*)&tile[orr * 72 + ks];
  uint4 o1 = *(const uint4*)&tile[orr * 72 + ks + 8];
  unsigned short* d = dst + (long)bz * dbs + (long)(bx * 64 + orr) * dld + by * 64 + ks;
  *(uint4*)d = o0;
  *(uint4*)(d + 8) = o1;
}

// ---- pre: blocks 0..1023 = router (fused x->bf16, NO global atomics);
//           blocks 1024..8703 = all 6 weight transposes ----
__global__ __launch_bounds__(256) void k_pre(
    const float* __restrict__ x, const float* __restrict__ wr,
    const float* __restrict__ wshg,
    const float* __restrict__ wg, const float* __restrict__ wu,
    const float* __restrict__ wd, const float* __restrict__ wsg,
    const float* __restrict__ wsu, const float* __restrict__ wsd,
    unsigned short* __restrict__ xb, float* __restrict__ logits_out,
    int* __restrict__ top_i, float* __restrict__ top_w, float* __restrict__ gate_sig,
    unsigned short* __restrict__ WGUT, unsigned short* __restrict__ WDT,
    unsigned short* __restrict__ WSGUT, unsigned short* __restrict__ WSDT) {
  __shared__ float red[4][17];
  int id = blockIdx.x;
  if (id >= T_) {
    id -= T_;
    if (id < 4096) {
      const float* s = id < 2048 ? wg : wu;
      unsigned short* dd = id < 2048 ? WGUT : WGUT + (size_t)I_ * H_;
      int l = id & 2047;
      int bz = l >> 7, r = l & 127;
      transpose_tile(s, dd, I_, H_, (long)H_ * I_, (long)2 * I_ * H_, r & 7, r >> 3, bz);
    } else if (id < 6144) {
      int l = id - 4096;
      int bz = l >> 7, r = l & 127;
      transpose_tile(wd, WDT, H_, I_, (long)I_ * H_, (long)H_ * I_, r & 15, r >> 4, bz);
    } else if (id < 7168) {
      int l = id - 6144;
      const float* s = l < 512 ? wsg : wsu;
      unsigned short* dd = l < 512 ? WSGUT : WSGUT + (size_t)IS_ * H_;
      l &= 511;
      transpose_tile(s, dd, IS_, H_, 0, 0, l & 31, l >> 5, 0);
    } else {
      int l = id - 7168;
      transpose_tile(wsd, WSDT, H_, IS_, 0, 0, l & 15, l >> 4, 0);
    }
    return;
  }
  int t = id, tid = threadIdx.x;
  int h0 = tid << 2;
  float acc[17];
#pragma unroll
  for (int e = 0; e < 17; e++) acc[e] = 0.f;
  float4 xv = *(const float4*)(x + (long)t * H_ + h0);
  float4 wsh = *(const float4*)(wshg + h0);
  ushort4 xo;
  xo.x = f2bf(xv.x); xo.y = f2bf(xv.y); xo.z = f2bf(xv.z); xo.w = f2bf(xv.w);
  *(ushort4*)(xb + (long)t * H_ + h0) = xo;
  float xs[4] = {xv.x, xv.y, xv.z, xv.w};
  float ws[4] = {wsh.x, wsh.y, wsh.z, wsh.w};
#pragma unroll
  for (int j = 0; j < 4; j++) {
    const float4* w4 = (const float4*)(wr + (long)(h0 + j) * 16);
    float4 w0 = w4[0], w1 = w4[1], w2 = w4[2], w3 = w4[3];
    float xvj = xs[j];
    acc[0] += xvj * w0.x; acc[1] += xvj * w0.y; acc[2] += xvj * w0.z; acc[3] += xvj * w0.w;
    acc[4] += xvj * w1.x; acc[5] += xvj * w1.y; acc[6] += xvj * w1.z; acc[7] += xvj * w1.w;
    acc[8] += xvj * w2.x; acc[9] += xvj * w2.y; acc[10] += xvj * w2.z; acc[11] += xvj * w2.w;
    acc[12] += xvj * w3.x; acc[13] += xvj * w3.y; acc[14] += xvj * w3.z; acc[15] += xvj * w3.w;
    acc[16] += xvj * ws[j];
  }
#pragma unroll
  for (int off = 32; off >= 1; off >>= 1) {
#pragma unroll
    for (int e = 0; e < 17; e++) acc[e] += __shfl_xor(acc[e], off, 64);
  }
  int wid = tid >> 6, lane = tid & 63;
  if (lane == 0) {
#pragma unroll
    for (int e = 0; e < 17; e++) red[wid][e] = acc[e];
  }
  __syncthreads();
  if (tid == 0) {
    float a[17];
#pragma unroll
    for (int e = 0; e < 17; e++)
      a[e] = red[0][e] + red[1][e] + red[2][e] + red[3][e];
    float m = a[0];
#pragma unroll
    for (int e = 1; e < 16; e++) m = fmaxf(m, a[e]);
    float p[16], s = 0.f;
#pragma unroll
    for (int e = 0; e < 16; e++) { p[e] = expf(a[e] - m); s += p[e]; }
    float inv = 1.f / s;
#pragma unroll
    for (int e = 0; e < 16; e++) p[e] *= inv;
    int ti[4]; float tw[4]; float tsum = 0.f;
#pragma unroll
    for (int k = 0; k < 4; k++) {
      float best = -1.f; int bi = 0;
#pragma unroll
      for (int e = 0; e < 16; e++)
        if (p[e] > best) { best = p[e]; bi = e; }
      ti[k] = bi; tw[k] = best; tsum += best; p[bi] = -2.f;
    }
    float rn = 1.f / tsum;
#pragma unroll
    for (int e = 0; e < 16; e++) logits_out[(long)t * 16 + e] = a[e];
#pragma unroll
    for (int k = 0; k < 4; k++) {
      top_i[t * 4 + k] = ti[k];
      top_w[t * 4 + k] = tw[k] * rn;
    }
    gate_sig[t] = 1.f / (1.f + expf(-a[16]));
  }
}

// ------- build: single block; histogram + prefix + scatter with LDS atomics -------
__global__ __launch_bounds__(256) void k_build(
    const int* __restrict__ top_i, int* __restrict__ counts,
    int* __restrict__ offsets, int* __restrict__ perm, int* __restrict__ slot_of) {
  __shared__ int cnt[E_], cur[E_];
  int tid = threadIdx.x;
  if (tid < E_) cnt[tid] = 0;
  __syncthreads();
  for (int i = tid; i < T_ * 4; i += 256)
    atomicAdd(&cnt[top_i[i]], 1);
  __syncthreads();
  if (tid == 0) {
    int run = 0;
    for (int e = 0; e < E_; e++) {
      int c = cnt[e];
      counts[e] = c;
      offsets[e] = run;
      cur[e] = run;
      run += c;
    }
  }
  __syncthreads();
  for (int i = tid; i < T_ * 4; i += 256) {
    int e = top_i[i];
    int pos = atomicAdd(&cur[e], 1);
    perm[pos] = i >> 2;
    slot_of[i] = pos;
  }
}

// ---- gate/up GEMM, 64x64 tile, dual-N (g and u share the A-tile), double-buffered,
//      counted-vmcnt pipeline (raw s_barrier; loads stay in flight across barrier),
//      silu(g)*u fused in-register, writes bf16 directly. ----
__global__ __launch_bounds__(256) void k_gemm_gu(
    const unsigned short* __restrict__ XB,
    const unsigned short* __restrict__ WSGUT, const unsigned short* __restrict__ WGUT,
    unsigned short* __restrict__ HSB, unsigned short* __restrict__ HB,
    const int* __restrict__ counts, const int* __restrict__ offsets,
    const int* __restrict__ perm) {
  int z = blockIdx.z;
  int mtile = blockIdx.y * 64;
  int ntile = blockIdx.x * 64;
  int M, row_base, uoff, ldd;
  const unsigned short* B0;
  unsigned short* DST;
  const int* pp;
  if (z == 0) {
    M = T_; row_base = 0; B0 = WSGUT; uoff = IS_;
    DST = HSB; ldd = IS_; pp = nullptr;
  } else {
    if (ntile >= I_) return;
    int e = z - 1;
    M = counts[e];
    if (mtile >= M) return;
    row_base = offsets[e];
    B0 = WGUT + (long)e * 2 * I_ * H_;
    uoff = I_;
    DST = HB; ldd = I_; pp = perm;
  }

  __shared__ unsigned short lds[2][6144];  // As 0..2047 | Bg 2048..4095 | Bu 4096..6143

  int tid = threadIdx.x, wid = tid >> 6, lane = tid & 63;
  int sub = lane >> 2;
  int ksw = ((lane & 3) ^ ((sub >> 1) & 3)) << 3;  // swizzled k-chunk (shorts)

  int rm = mtile + wid * 16 + sub;
  if (rm > M - 1) rm = M - 1;
  long arow = pp ? (long)pp[row_base + rm] : (long)(row_base + rm);
  const unsigned short* aptr = XB + arow * H_ + ksw;
  int rbn = ntile + wid * 16 + sub;
  const unsigned short* bgptr = B0 + (long)rbn * H_ + ksw;
  const unsigned short* buptr = B0 + (long)(rbn + uoff) * H_ + ksw;
  int soff = wid * 512;

  int fr = lane & 15, quad = lane >> 4;
  int fslot = (quad ^ ((fr >> 1) & 3)) << 3;
  int wm = (wid >> 1) * 32, wn = (wid & 1) * 32;

  f32x4 acc[2][2][2];
#pragma unroll
  for (int h = 0; h < 2; h++)
#pragma unroll
    for (int i = 0; i < 2; i++)
#pragma unroll
      for (int j = 0; j < 2; j++) acc[h][i][j] = (f32x4){0.f, 0.f, 0.f, 0.f};

  const int NK = H_ / 32;
  gload16(aptr, &lds[0][soff]);
  gload16(bgptr, &lds[0][2048 + soff]);
  gload16(buptr, &lds[0][4096 + soff]);

  for (int kt = 0; kt < NK; kt++) {
    int cur = kt & 1;
    if (kt + 1 < NK) {
      int ko = (kt + 1) * 32;
      // stage next tile into the other buffer; its previous readers all passed
      // the end-of-iter barrier last iteration, so overwrite is safe.
      gload16(aptr + ko, &lds[cur ^ 1][soff]);
      gload16(bgptr + ko, &lds[cur ^ 1][2048 + soff]);
      gload16(buptr + ko, &lds[cur ^ 1][4096 + soff]);
      // wait only for the PREVIOUS iter's 3 loads (this buffer); the 3 just
      // issued stay in flight across the barrier.
      asm volatile("s_waitcnt vmcnt(3)" ::: "memory");
    } else {
      asm volatile("s_waitcnt vmcnt(0)" ::: "memory");
    }
    __builtin_amdgcn_s_barrier();
    __builtin_amdgcn_sched_barrier(0);
    const unsigned short* As = &lds[cur][0];
    const unsigned short* Bg = &lds[cur][2048];
    const unsigned short* Bu = &lds[cur][4096];
    short8 af[2], bg[2], bu[2];
#pragma unroll
    for (int i = 0; i < 2; i++)
      af[i] = *(const short8*)(&As[(wm + i * 16 + fr) * 32 + fslot]);
#pragma unroll
    for (int j = 0; j < 2; j++) {
      bg[j] = *(const short8*)(&Bg[(wn + j * 16 + fr) * 32 + fslot]);
      bu[j] = *(const short8*)(&Bu[(wn + j * 16 + fr) * 32 + fslot]);
    }
#pragma unroll
    for (int i = 0; i < 2; i++)
#pragma unroll
      for (int j = 0; j < 2; j++) {
        acc[0][i][j] = __builtin_amdgcn_mfma_f32_16x16x32_bf16(af[i], bg[j], acc[0][i][j], 0, 0, 0);
        acc[1][i][j] = __builtin_amdgcn_mfma_f32_16x16x32_bf16(af[i], bu[j], acc[1][i][j], 0, 0, 0);
      }
    // all ds_reads of lds[cur] drained before anyone may restage into it
    asm volatile("s_waitcnt lgkmcnt(0)" ::: "memory");
    __builtin_amdgcn_sched_barrier(0);
    __builtin_amdgcn_s_barrier();
  }

#pragma unroll
  for (int i = 0; i < 2; i++) {
    int m0 = mtile + wm + i * 16 + quad * 4;
#pragma unroll
    for (int j = 0; j < 2; j++) {
      int col = ntile + wn + j * 16 + fr;
#pragma unroll
      for (int r = 0; r < 4; r++) {
        int m = m0 + r;
        if (m < M) {
          float g = acc[0][i][j][r], u = acc[1][i][j][r];
          DST[(long)(row_base + m) * ldd + col] = f2bf(g / (1.f + expf(-g)) * u);
        }
      }
    }
  }
}

// ---- down GEMM, 64x64 tile, double-buffered, counted-vmcnt pipeline, fp32 out ----
__global__ __launch_bounds__(256) void k_gemm_dn(
    const unsigned short* __restrict__ HSB, const unsigned short* __restrict__ WSDT,
    float* __restrict__ SHOUT,
    const unsigned short* __restrict__ HB, const unsigned short* __restrict__ WDT,
    float* __restrict__ YD,
    const int* __restrict__ counts, const int* __restrict__ offsets) {
  int z = blockIdx.z;
  int mtile = blockIdx.y * 64;
  int ntile = blockIdx.x * 64;
  const unsigned short *A, *B;
  int K, M, rb;
  float* Y;
  if (z == 0) {
    A = HSB; K = IS_; M = T_; rb = 0; B = WSDT; Y = SHOUT;
  } else {
    int e = z - 1;
    M = counts[e];
    if (mtile >= M) return;
    rb = offsets[e];
    A = HB; K = I_; B = WDT + (long)e * H_ * I_; Y = YD;
  }

  __shared__ unsigned short lds[2][4096];  // As 0..2047 | Bs 2048..4095

  int tid = threadIdx.x, wid = tid >> 6, lane = tid & 63;
  int sub = lane >> 2;
  int ksw = ((lane & 3) ^ ((sub >> 1) & 3)) << 3;

  int rm = mtile + wid * 16 + sub;
  if (rm > M - 1) rm = M - 1;
  const unsigned short* aptr = A + (long)(rb + rm) * K + ksw;
  int rbn = ntile + wid * 16 + sub;
  const unsigned short* bptr = B + (long)rbn * K + ksw;
  int soff = wid * 512;

  int fr = lane & 15, quad = lane >> 4;
  int fslot = (quad ^ ((fr >> 1) & 3)) << 3;
  int wm = (wid >> 1) * 32, wn = (wid & 1) * 32;

  f32x4 acc[2][2];
#pragma unroll
  for (int i = 0; i < 2; i++)
#pragma unroll
    for (int j = 0; j < 2; j++) acc[i][j] = (f32x4){0.f, 0.f, 0.f, 0.f};

  const int NK = K / 32;
  gload16(aptr, &lds[0][soff]);
  gload16(bptr, &lds[0][2048 + soff]);

  for (int kt = 0; kt < NK; kt++) {
    int cur = kt & 1;
    if (kt + 1 < NK) {
      int ko = (kt + 1) * 32;
      gload16(aptr + ko, &lds[cur ^ 1][soff]);
      gload16(bptr + ko, &lds[cur ^ 1][2048 + soff]);
      asm volatile("s_waitcnt vmcnt(2)" ::: "memory");
    } else {
      asm volatile("s_waitcnt vmcnt(0)" ::: "memory");
    }
    __builtin_amdgcn_s_barrier();
    __builtin_amdgcn_sched_barrier(0);
    const unsigned short* As = &lds[cur][0];
    const unsigned short* Bs = &lds[cur][2048];
    short8 af[2], bf[2];
#pragma unroll
    for (int i = 0; i < 2; i++)
      af[i] = *(const short8*)(&As[(wm + i * 16 + fr) * 32 + fslot]);
#pragma unroll
    for (int j = 0; j < 2; j++)
      bf[j] = *(const short8*)(&Bs[(wn + j * 16 + fr) * 32 + fslot]);
#pragma unroll
    for (int i = 0; i < 2; i++)
#pragma unroll
      for (int j = 0; j < 2; j++)
        acc[i][j] = __builtin_amdgcn_mfma_f32_16x16x32_bf16(af[i], bf[j], acc[i][j], 0, 0, 0);
    asm volatile("s_waitcnt lgkmcnt(0)" ::: "memory");
    __builtin_amdgcn_sched_barrier(0);
    __builtin_amdgcn_s_barrier();
  }

#pragma unroll
  for (int i = 0; i < 2; i++) {
    int m0 = mtile + wm + i * 16 + quad * 4;
#pragma unroll
    for (int j = 0; j < 2; j++) {
      int col = ntile + wn + j * 16 + fr;
#pragma unroll
      for (int r = 0; r < 4; r++) {
        int m = m0 + r;
        if (m < M) Y[(long)(rb + m) * H_ + col] = acc[i][j][r];
      }
    }
  }
}

// ---------------- combine: out = sum_k w*Yd[slot] + sig*shared ----------------
__global__ __launch_bounds__(256) void k_combine(
    const float* __restrict__ Yd, const float* __restrict__ shout,
    const float* __restrict__ gate_sig, const float* __restrict__ top_w,
    const int* __restrict__ slot_of, float* __restrict__ out) {
  int t = blockIdx.x;
  int c = threadIdx.x << 2;
  float4 sh = *(const float4*)(shout + (long)t * H_ + c);
  float gs = gate_sig[t];
  float4 o;
  o.x = gs * sh.x; o.y = gs * sh.y; o.z = gs * sh.z; o.w = gs * sh.w;
#pragma unroll
  for (int k = 0; k < 4; k++) {
    int s = slot_of[t * 4 + k];
    float w = top_w[t * 4 + k];
    float4 v = *(const float4*)(Yd + (long)s * H_ + c);
    o.x += w * v.x; o.y += w * v.y; o.z += w * v.z; o.w += w * v.w;
  }
  *(float4*)(out + (long)t * H_ + c) = o;
}

extern "C" void kernel_launch(void* const* d_in, const int* in_sizes, int n_in,
                              void* d_out, int out_size, void* d_ws, size_t ws_size,
                              hipStream_t stream) {
  const float* x    = (const float*)d_in[0];
  const float* wrt  = (const float*)d_in[1];
  const float* wg   = (const float*)d_in[2];
  const float* wu   = (const float*)d_in[3];
  const float* wd   = (const float*)d_in[4];
  const float* wsg  = (const float*)d_in[5];
  const float* wsu  = (const float*)d_in[6];
  const float* wsd  = (const float*)d_in[7];
  const float* wshg = (const float*)d_in[8];
  float* out = (float*)d_out;
  float* logits_out = out + (long)T_ * H_;

  char* ws = (char*)d_ws;
  size_t off = 0;
  auto take = [&](size_t bytes) -> void* {
    void* p = ws + off;
    off += (bytes + 255) & ~(size_t)255;
    return p;
  };

  unsigned short* XB    = (unsigned short*)take((size_t)T_ * H_ * 2);
  unsigned short* WGUT  = (unsigned short*)take((size_t)E_ * 2 * I_ * H_ * 2);  // [e][g|u rows][h]
  unsigned short* WDT   = (unsigned short*)take((size_t)E_ * H_ * I_ * 2);      // [e][n=H][k=I]
  unsigned short* WSGUT = (unsigned short*)take((size_t)2 * IS_ * H_ * 2);      // [g|u rows][h]
  unsigned short* WSDT  = (unsigned short*)take((size_t)H_ * IS_ * 2);          // [n=H][k=IS]
  float*          YD    = (float*)take((size_t)4096 * H_ * 4);                  // expert down out
  unsigned short* HSB   = (unsigned short*)take((size_t)T_ * IS_ * 2);
  float*          SHOUT = (float*)take((size_t)T_ * H_ * 4);
  unsigned short* HB    = (unsigned short*)take((size_t)4096 * I_ * 2);
  int*   counts   = (int*)take(64);
  int*   offsets  = (int*)take(64);
  int*   top_i    = (int*)take((size_t)T_ * 4 * 4);
  float* top_w    = (float*)take((size_t)T_ * 4 * 4);
  int*   perm     = (int*)take((size_t)4096 * 4);
  int*   slot_of  = (int*)take((size_t)4096 * 4);
  float* gate_sig = (float*)take((size_t)T_ * 4);

  // router (1024 blocks) + all weight transposes (7680 blocks) in one launch
  k_pre<<<8704, 256, 0, stream>>>(x, wrt, wshg, wg, wu, wd, wsg, wsu, wsd,
                                  XB, logits_out, top_i, top_w, gate_sig,
                                  WGUT, WDT, WSGUT, WSDT);
  k_build<<<1, 256, 0, stream>>>(top_i, counts, offsets, perm, slot_of);

  // fused gate/up + silu: 64x64 tiles. z=0 shared (32x16 live), z>=1 experts (x<8)
  k_gemm_gu<<<dim3(32, 16, 17), 256, 0, stream>>>(XB, WSGUT, WGUT, HSB, HB,
                                                  counts, offsets, perm);
  // down: 64x64 tiles. z=0 shared (16x16 live), z>=1 experts (16 x live)
  k_gemm_dn<<<dim3(16, 16, 17), 256, 0, stream>>>(HSB, WSDT, SHOUT, HB, WDT, YD,
                                                  counts, offsets);
  k_combine<<<T_, 256, 0, stream>>>(YD, SHOUT, gate_sig, top_w, slot_of, out);
}

// Round 2
// 253.077 us; speedup vs baseline: 1.1377x; 1.1053x over previous
//
#include <hip/hip_runtime.h>
#include <hip/hip_bf16.h>

#define T_ 1024
#define H_ 1024
#define I_ 512
#define IS_ 2048
#define E_ 16

typedef __attribute__((ext_vector_type(8))) short short8;
typedef __attribute__((ext_vector_type(4))) float f32x4;

__device__ __forceinline__ unsigned short f2bf(float f) {
  unsigned u = __builtin_bit_cast(unsigned, f);
  unsigned r = (u + 0x7fffu + ((u >> 16) & 1u)) >> 16;
  return (unsigned short)r;
}

__device__ __forceinline__ void gload16(const void* g, void* l) {
  __builtin_amdgcn_global_load_lds(
      (const __attribute__((address_space(1))) unsigned int*)g,
      (__attribute__((address_space(3))) unsigned int*)l, 16, 0, 0);
}

// ------------- transpose tile body: src fp32 [b][R][C] -> dst bf16 [b][C][R] -------------
__device__ __forceinline__ void transpose_tile(
    const float* __restrict__ src, unsigned short* __restrict__ dst,
    int C, int dld, long sbs, long dbs, int bx, int by, int bz) {
  __shared__ unsigned short tile[64 * 72];
  const float* s = src + (long)bz * sbs + ((long)by * 64) * C + bx * 64;
  int cgrp = threadIdx.x & 15, rgrp = threadIdx.x >> 4;
  int c = cgrp << 2, r0 = rgrp << 2;
  const float* sp = s + (long)r0 * C + c;
  float4 v0 = *(const float4*)(sp);
  float4 v1 = *(const float4*)(sp + C);
  float4 v2 = *(const float4*)(sp + 2 * C);
  float4 v3 = *(const float4*)(sp + 3 * C);
  ushort4 w;
  w = (ushort4){f2bf(v0.x), f2bf(v1.x), f2bf(v2.x), f2bf(v3.x)};
  *(ushort4*)&tile[(c + 0) * 72 + r0] = w;
  w = (ushort4){f2bf(v0.y), f2bf(v1.y), f2bf(v2.y), f2bf(v3.y)};
  *(ushort4*)&tile[(c + 1) * 72 + r0] = w;
  w = (ushort4){f2bf(v0.z), f2bf(v1.z), f2bf(v2.z), f2bf(v3.z)};
  *(ushort4*)&tile[(c + 2) * 72 + r0] = w;
  w = (ushort4){f2bf(v0.w), f2bf(v1.w), f2bf(v2.w), f2bf(v3.w)};
  *(ushort4*)&tile[(c + 3) * 72 + r0] = w;
  __syncthreads();
  int orr = threadIdx.x >> 2;
  int ks = (threadIdx.x & 3) << 4;
  uint4 o0 = *(const uint4*)&tile[orr * 72 + ks];
  uint4 o1 = *(const uint4*)&tile[orr * 72 + ks + 8];
  unsigned short* d = dst + (long)bz * dbs + (long)(bx * 64 + orr) * dld + by * 64 + ks;
  *(uint4*)d = o0;
  *(uint4*)(d + 8) = o1;
}

// ---- pre: blocks 0..1023 = router (fused x->bf16); blocks 1024..8703 = weight transposes ----
__global__ __launch_bounds__(256) void k_pre(
    const float* __restrict__ x, const float* __restrict__ wr,
    const float* __restrict__ wshg,
    const float* __restrict__ wg, const float* __restrict__ wu,
    const float* __restrict__ wd, const float* __restrict__ wsg,
    const float* __restrict__ wsu, const float* __restrict__ wsd,
    unsigned short* __restrict__ xb, float* __restrict__ logits_out,
    int* __restrict__ top_i, float* __restrict__ top_w, float* __restrict__ gate_sig,
    unsigned short* __restrict__ WGUT, unsigned short* __restrict__ WDT,
    unsigned short* __restrict__ WSGUT, unsigned short* __restrict__ WSDT) {
  __shared__ float red[4][17];
  int id = blockIdx.x;
  if (id >= T_) {
    id -= T_;
    if (id < 4096) {
      const float* s = id < 2048 ? wg : wu;
      unsigned short* dd = id < 2048 ? WGUT : WGUT + (size_t)I_ * H_;
      int l = id & 2047;
      int bz = l >> 7, r = l & 127;
      transpose_tile(s, dd, I_, H_, (long)H_ * I_, (long)2 * I_ * H_, r & 7, r >> 3, bz);
    } else if (id < 6144) {
      int l = id - 4096;
      int bz = l >> 7, r = l & 127;
      transpose_tile(wd, WDT, H_, I_, (long)I_ * H_, (long)H_ * I_, r & 15, r >> 4, bz);
    } else if (id < 7168) {
      int l = id - 6144;
      const float* s = l < 512 ? wsg : wsu;
      unsigned short* dd = l < 512 ? WSGUT : WSGUT + (size_t)IS_ * H_;
      l &= 511;
      transpose_tile(s, dd, IS_, H_, 0, 0, l & 31, l >> 5, 0);
    } else {
      int l = id - 7168;
      transpose_tile(wsd, WSDT, H_, IS_, 0, 0, l & 15, l >> 4, 0);
    }
    return;
  }
  int t = id, tid = threadIdx.x;
  int h0 = tid << 2;
  float acc[17];
#pragma unroll
  for (int e = 0; e < 17; e++) acc[e] = 0.f;
  float4 xv = *(const float4*)(x + (long)t * H_ + h0);
  float4 wsh = *(const float4*)(wshg + h0);
  ushort4 xo;
  xo.x = f2bf(xv.x); xo.y = f2bf(xv.y); xo.z = f2bf(xv.z); xo.w = f2bf(xv.w);
  *(ushort4*)(xb + (long)t * H_ + h0) = xo;
  float xs[4] = {xv.x, xv.y, xv.z, xv.w};
  float ws[4] = {wsh.x, wsh.y, wsh.z, wsh.w};
#pragma unroll
  for (int j = 0; j < 4; j++) {
    const float4* w4 = (const float4*)(wr + (long)(h0 + j) * 16);
    float4 w0 = w4[0], w1 = w4[1], w2 = w4[2], w3 = w4[3];
    float xvj = xs[j];
    acc[0] += xvj * w0.x; acc[1] += xvj * w0.y; acc[2] += xvj * w0.z; acc[3] += xvj * w0.w;
    acc[4] += xvj * w1.x; acc[5] += xvj * w1.y; acc[6] += xvj * w1.z; acc[7] += xvj * w1.w;
    acc[8] += xvj * w2.x; acc[9] += xvj * w2.y; acc[10] += xvj * w2.z; acc[11] += xvj * w2.w;
    acc[12] += xvj * w3.x; acc[13] += xvj * w3.y; acc[14] += xvj * w3.z; acc[15] += xvj * w3.w;
    acc[16] += xvj * ws[j];
  }
#pragma unroll
  for (int off = 32; off >= 1; off >>= 1) {
#pragma unroll
    for (int e = 0; e < 17; e++) acc[e] += __shfl_xor(acc[e], off, 64);
  }
  int wid = tid >> 6, lane = tid & 63;
  if (lane == 0) {
#pragma unroll
    for (int e = 0; e < 17; e++) red[wid][e] = acc[e];
  }
  __syncthreads();
  if (tid == 0) {
    float a[17];
#pragma unroll
    for (int e = 0; e < 17; e++)
      a[e] = red[0][e] + red[1][e] + red[2][e] + red[3][e];
    float m = a[0];
#pragma unroll
    for (int e = 1; e < 16; e++) m = fmaxf(m, a[e]);
    float p[16], s = 0.f;
#pragma unroll
    for (int e = 0; e < 16; e++) { p[e] = expf(a[e] - m); s += p[e]; }
    float inv = 1.f / s;
#pragma unroll
    for (int e = 0; e < 16; e++) p[e] *= inv;
    int ti[4]; float tw[4]; float tsum = 0.f;
#pragma unroll
    for (int k = 0; k < 4; k++) {
      float best = -1.f; int bi = 0;
#pragma unroll
      for (int e = 0; e < 16; e++)
        if (p[e] > best) { best = p[e]; bi = e; }
      ti[k] = bi; tw[k] = best; tsum += best; p[bi] = -2.f;
    }
    float rn = 1.f / tsum;
#pragma unroll
    for (int e = 0; e < 16; e++) logits_out[(long)t * 16 + e] = a[e];
#pragma unroll
    for (int k = 0; k < 4; k++) {
      top_i[t * 4 + k] = ti[k];
      top_w[t * 4 + k] = tw[k] * rn;
    }
    gate_sig[t] = 1.f / (1.f + expf(-a[16]));
  }
}

// ------- build: histogram + prefix + scatter + compact tile worklists -------
// tile word: z[12+] | y[6:11] | x[0:5];  z==0 -> shared expert
__global__ __launch_bounds__(256) void k_build(
    const int* __restrict__ top_i, int* __restrict__ counts,
    int* __restrict__ offsets, int* __restrict__ perm, int* __restrict__ slot_of,
    int* __restrict__ gu_tiles, int* __restrict__ dn_tiles, int* __restrict__ ntl) {
  __shared__ int cnt[E_], cur[E_], mt[E_], pg[E_];
  int tid = threadIdx.x;
  if (tid < E_) cnt[tid] = 0;
  __syncthreads();
  for (int i = tid; i < T_ * 4; i += 256)
    atomicAdd(&cnt[top_i[i]], 1);
  __syncthreads();
  if (tid == 0) {
    int run = 0, trun = 0;
    for (int e = 0; e < E_; e++) {
      int c = cnt[e];
      counts[e] = c;
      offsets[e] = run;
      cur[e] = run;
      run += c;
      mt[e] = (c + 63) >> 6;
      pg[e] = trun;
      trun += mt[e];
    }
    ntl[0] = 512 + trun * 8;   // gu tiles
    ntl[1] = 256 + trun * 16;  // dn tiles
  }
  __syncthreads();
  for (int i = tid; i < T_ * 4; i += 256) {
    int e = top_i[i];
    int pos = atomicAdd(&cur[e], 1);
    perm[pos] = i >> 2;
    slot_of[i] = pos;
  }
  // shared-expert tiles first (dn's are the long K=2048 ones -> LPT order)
  for (int i = tid; i < 512; i += 256)
    gu_tiles[i] = ((i >> 5) << 6) | (i & 31);
  if (tid < 256)
    dn_tiles[tid] = ((tid >> 4) << 6) | (tid & 15);
  int trun = pg[E_ - 1] + mt[E_ - 1];
  for (int i = tid; i < trun * 8; i += 256) {
    int m = i >> 3, x = i & 7;
    int e = 0;
    while (e < E_ - 1 && m >= pg[e] + mt[e]) e++;
    int y = m - pg[e];
    gu_tiles[512 + i] = ((e + 1) << 12) | (y << 6) | x;
  }
  for (int i = tid; i < trun * 16; i += 256) {
    int m = i >> 4, x = i & 15;
    int e = 0;
    while (e < E_ - 1 && m >= pg[e] + mt[e]) e++;
    int y = m - pg[e];
    dn_tiles[256 + i] = ((e + 1) << 12) | (y << 6) | x;
  }
}

// ---- gate/up GEMM, 64x64 tile, dual-N, depth-3 pipeline (stage distance 2),
//      ONE barrier per K-iter, counted vmcnt, worklist-driven grid. ----
__global__ __launch_bounds__(256) void k_gemm_gu(
    const unsigned short* __restrict__ XB,
    const unsigned short* __restrict__ WSGUT, const unsigned short* __restrict__ WGUT,
    unsigned short* __restrict__ HSB, unsigned short* __restrict__ HB,
    const int* __restrict__ counts, const int* __restrict__ offsets,
    const int* __restrict__ perm, const int* __restrict__ gu_tiles,
    const int* __restrict__ ntl) {
  __shared__ unsigned short lds[3][6144];  // per stage: As 0..2047 | Bg 2048..4095 | Bu 4096..6143

  int tid = threadIdx.x, wid = tid >> 6, lane = tid & 63;
  int sub = lane >> 2;
  int ksw = ((lane & 3) ^ ((sub >> 1) & 3)) << 3;  // swizzled k-chunk (shorts)
  int soff = wid * 512;
  int fr = lane & 15, quad = lane >> 4;
  int fslot = (quad ^ ((fr >> 1) & 3)) << 3;
  int wm = (wid >> 1) * 32, wn = (wid & 1) * 32;

  int n_tiles = ntl[0];
  for (int w = blockIdx.x; w < n_tiles; w += gridDim.x) {
    int twd = gu_tiles[w];
    int z = twd >> 12;
    int mtile = ((twd >> 6) & 63) * 64;
    int ntile = (twd & 63) * 64;
    int M, row_base, uoff, ldd;
    const unsigned short* B0;
    unsigned short* DST;
    const int* pp;
    if (z == 0) {
      M = T_; row_base = 0; B0 = WSGUT; uoff = IS_;
      DST = HSB; ldd = IS_; pp = nullptr;
    } else {
      int e = z - 1;
      M = counts[e];
      row_base = offsets[e];
      B0 = WGUT + (long)e * 2 * I_ * H_;
      uoff = I_;
      DST = HB; ldd = I_; pp = perm;
    }

    int rm = mtile + wid * 16 + sub;
    if (rm > M - 1) rm = M - 1;
    long arow = pp ? (long)pp[row_base + rm] : (long)(row_base + rm);
    const unsigned short* aptr = XB + arow * H_ + ksw;
    int rbn = ntile + wid * 16 + sub;
    const unsigned short* bgptr = B0 + (long)rbn * H_ + ksw;
    const unsigned short* buptr = B0 + (long)(rbn + uoff) * H_ + ksw;

    f32x4 acc[2][2][2];
#pragma unroll
    for (int h = 0; h < 2; h++)
#pragma unroll
      for (int i = 0; i < 2; i++)
#pragma unroll
        for (int j = 0; j < 2; j++) acc[h][i][j] = (f32x4){0.f, 0.f, 0.f, 0.f};

    auto STAGE = [&](int slot, int kt) {
      int ko = kt * 32;
      unsigned short* base = &lds[slot][0];
      gload16(aptr + ko, base + soff);
      gload16(bgptr + ko, base + 2048 + soff);
      gload16(buptr + ko, base + 4096 + soff);
    };

    const int NK = H_ / 32;
    // all waves done reading LDS from the previous worklist tile
    asm volatile("s_waitcnt lgkmcnt(0)" ::: "memory");
    __builtin_amdgcn_s_barrier();
    __builtin_amdgcn_sched_barrier(0);
    STAGE(0, 0);
    STAGE(1, 1);
    int cur = 0, stg = 2;
    for (int kt = 0; kt < NK; kt++) {
      // my tile-kt loads landed (allow tile kt+1's 3 loads in flight)
      if (kt + 1 < NK) asm volatile("s_waitcnt vmcnt(3)" ::: "memory");
      else             asm volatile("s_waitcnt vmcnt(0)" ::: "memory");
      __builtin_amdgcn_s_barrier();  // => ALL waves' tile-kt loads landed;
                                     //    all waves drained reads of tile kt-1
      __builtin_amdgcn_sched_barrier(0);
      if (kt + 2 < NK) STAGE(stg, kt + 2);  // overwrites slot of tile kt-1: safe
      __builtin_amdgcn_sched_barrier(0);
      const unsigned short* As = &lds[cur][0];
      const unsigned short* Bg = &lds[cur][2048];
      const unsigned short* Bu = &lds[cur][4096];
      short8 af[2], bg[2], bu[2];
#pragma unroll
      for (int i = 0; i < 2; i++)
        af[i] = *(const short8*)(&As[(wm + i * 16 + fr) * 32 + fslot]);
#pragma unroll
      for (int j = 0; j < 2; j++) {
        bg[j] = *(const short8*)(&Bg[(wn + j * 16 + fr) * 32 + fslot]);
        bu[j] = *(const short8*)(&Bu[(wn + j * 16 + fr) * 32 + fslot]);
      }
#pragma unroll
      for (int i = 0; i < 2; i++)
#pragma unroll
        for (int j = 0; j < 2; j++) {
          acc[0][i][j] = __builtin_amdgcn_mfma_f32_16x16x32_bf16(af[i], bg[j], acc[0][i][j], 0, 0, 0);
          acc[1][i][j] = __builtin_amdgcn_mfma_f32_16x16x32_bf16(af[i], bu[j], acc[1][i][j], 0, 0, 0);
        }
      asm volatile("s_waitcnt lgkmcnt(0)" ::: "memory");
      __builtin_amdgcn_sched_barrier(0);
      cur = (cur == 2) ? 0 : cur + 1;
      stg = (stg == 2) ? 0 : stg + 1;
    }

#pragma unroll
    for (int i = 0; i < 2; i++) {
      int m0 = mtile + wm + i * 16 + quad * 4;
#pragma unroll
      for (int j = 0; j < 2; j++) {
        int col = ntile + wn + j * 16 + fr;
#pragma unroll
        for (int r = 0; r < 4; r++) {
          int m = m0 + r;
          if (m < M) {
            float g = acc[0][i][j][r], u = acc[1][i][j][r];
            DST[(long)(row_base + m) * ldd + col] = f2bf(g / (1.f + expf(-g)) * u);
          }
        }
      }
    }
  }
}

// ---- down GEMM, 64x64 tile, depth-3 pipeline, one barrier/iter, worklist, fp32 out ----
__global__ __launch_bounds__(256) void k_gemm_dn(
    const unsigned short* __restrict__ HSB, const unsigned short* __restrict__ WSDT,
    float* __restrict__ SHOUT,
    const unsigned short* __restrict__ HB, const unsigned short* __restrict__ WDT,
    float* __restrict__ YD,
    const int* __restrict__ counts, const int* __restrict__ offsets,
    const int* __restrict__ dn_tiles, const int* __restrict__ ntl) {
  __shared__ unsigned short lds[3][4096];  // per stage: As 0..2047 | Bs 2048..4095

  int tid = threadIdx.x, wid = tid >> 6, lane = tid & 63;
  int sub = lane >> 2;
  int ksw = ((lane & 3) ^ ((sub >> 1) & 3)) << 3;
  int soff = wid * 512;
  int fr = lane & 15, quad = lane >> 4;
  int fslot = (quad ^ ((fr >> 1) & 3)) << 3;
  int wm = (wid >> 1) * 32, wn = (wid & 1) * 32;

  int n_tiles = ntl[1];
  for (int w = blockIdx.x; w < n_tiles; w += gridDim.x) {
    int twd = dn_tiles[w];
    int z = twd >> 12;
    int mtile = ((twd >> 6) & 63) * 64;
    int ntile = (twd & 63) * 64;
    const unsigned short *A, *B;
    int K, M, rb;
    float* Y;
    if (z == 0) {
      A = HSB; K = IS_; M = T_; rb = 0; B = WSDT; Y = SHOUT;
    } else {
      int e = z - 1;
      M = counts[e];
      rb = offsets[e];
      A = HB; K = I_; B = WDT + (long)e * H_ * I_; Y = YD;
    }

    int rm = mtile + wid * 16 + sub;
    if (rm > M - 1) rm = M - 1;
    const unsigned short* aptr = A + (long)(rb + rm) * K + ksw;
    int rbn = ntile + wid * 16 + sub;
    const unsigned short* bptr = B + (long)rbn * K + ksw;

    f32x4 acc[2][2];
#pragma unroll
    for (int i = 0; i < 2; i++)
#pragma unroll
      for (int j = 0; j < 2; j++) acc[i][j] = (f32x4){0.f, 0.f, 0.f, 0.f};

    auto STAGE = [&](int slot, int kt) {
      int ko = kt * 32;
      unsigned short* base = &lds[slot][0];
      gload16(aptr + ko, base + soff);
      gload16(bptr + ko, base + 2048 + soff);
    };

    const int NK = K / 32;
    asm volatile("s_waitcnt lgkmcnt(0)" ::: "memory");
    __builtin_amdgcn_s_barrier();
    __builtin_amdgcn_sched_barrier(0);
    STAGE(0, 0);
    STAGE(1, 1);
    int cur = 0, stg = 2;
    for (int kt = 0; kt < NK; kt++) {
      if (kt + 1 < NK) asm volatile("s_waitcnt vmcnt(2)" ::: "memory");
      else             asm volatile("s_waitcnt vmcnt(0)" ::: "memory");
      __builtin_amdgcn_s_barrier();
      __builtin_amdgcn_sched_barrier(0);
      if (kt + 2 < NK) STAGE(stg, kt + 2);
      __builtin_amdgcn_sched_barrier(0);
      const unsigned short* As = &lds[cur][0];
      const unsigned short* Bs = &lds[cur][2048];
      short8 af[2], bf[2];
#pragma unroll
      for (int i = 0; i < 2; i++)
        af[i] = *(const short8*)(&As[(wm + i * 16 + fr) * 32 + fslot]);
#pragma unroll
      for (int j = 0; j < 2; j++)
        bf[j] = *(const short8*)(&Bs[(wn + j * 16 + fr) * 32 + fslot]);
#pragma unroll
      for (int i = 0; i < 2; i++)
#pragma unroll
        for (int j = 0; j < 2; j++)
          acc[i][j] = __builtin_amdgcn_mfma_f32_16x16x32_bf16(af[i], bf[j], acc[i][j], 0, 0, 0);
      asm volatile("s_waitcnt lgkmcnt(0)" ::: "memory");
      __builtin_amdgcn_sched_barrier(0);
      cur = (cur == 2) ? 0 : cur + 1;
      stg = (stg == 2) ? 0 : stg + 1;
    }

#pragma unroll
    for (int i = 0; i < 2; i++) {
      int m0 = mtile + wm + i * 16 + quad * 4;
#pragma unroll
      for (int j = 0; j < 2; j++) {
        int col = ntile + wn + j * 16 + fr;
#pragma unroll
        for (int r = 0; r < 4; r++) {
          int m = m0 + r;
          if (m < M) Y[(long)(rb + m) * H_ + col] = acc[i][j][r];
        }
      }
    }
  }
}

// ---------------- combine: out = sum_k w*Yd[slot] + sig*shared ----------------
__global__ __launch_bounds__(256) void k_combine(
    const float* __restrict__ Yd, const float* __restrict__ shout,
    const float* __restrict__ gate_sig, const float* __restrict__ top_w,
    const int* __restrict__ slot_of, float* __restrict__ out) {
  int t = blockIdx.x;
  int c = threadIdx.x << 2;
  float4 sh = *(const float4*)(shout + (long)t * H_ + c);
  float gs = gate_sig[t];
  float4 o;
  o.x = gs * sh.x; o.y = gs * sh.y; o.z = gs * sh.z; o.w = gs * sh.w;
#pragma unroll
  for (int k = 0; k < 4; k++) {
    int s = slot_of[t * 4 + k];
    float w = top_w[t * 4 + k];
    float4 v = *(const float4*)(Yd + (long)s * H_ + c);
    o.x += w * v.x; o.y += w * v.y; o.z += w * v.z; o.w += w * v.w;
  }
  *(float4*)(out + (long)t * H_ + c) = o;
}

extern "C" void kernel_launch(void* const* d_in, const int* in_sizes, int n_in,
                              void* d_out, int out_size, void* d_ws, size_t ws_size,
                              hipStream_t stream) {
  const float* x    = (const float*)d_in[0];
  const float* wrt  = (const float*)d_in[1];
  const float* wg   = (const float*)d_in[2];
  const float* wu   = (const float*)d_in[3];
  const float* wd   = (const float*)d_in[4];
  const float* wsg  = (const float*)d_in[5];
  const float* wsu  = (const float*)d_in[6];
  const float* wsd  = (const float*)d_in[7];
  const float* wshg = (const float*)d_in[8];
  float* out = (float*)d_out;
  float* logits_out = out + (long)T_ * H_;

  char* ws = (char*)d_ws;
  size_t off = 0;
  auto take = [&](size_t bytes) -> void* {
    void* p = ws + off;
    off += (bytes + 255) & ~(size_t)255;
    return p;
  };

  unsigned short* XB    = (unsigned short*)take((size_t)T_ * H_ * 2);
  unsigned short* WGUT  = (unsigned short*)take((size_t)E_ * 2 * I_ * H_ * 2);  // [e][g|u rows][h]
  unsigned short* WDT   = (unsigned short*)take((size_t)E_ * H_ * I_ * 2);      // [e][n=H][k=I]
  unsigned short* WSGUT = (unsigned short*)take((size_t)2 * IS_ * H_ * 2);      // [g|u rows][h]
  unsigned short* WSDT  = (unsigned short*)take((size_t)H_ * IS_ * 2);          // [n=H][k=IS]
  float*          YD    = (float*)take((size_t)4096 * H_ * 4);                  // expert down out
  unsigned short* HSB   = (unsigned short*)take((size_t)T_ * IS_ * 2);
  float*          SHOUT = (float*)take((size_t)T_ * H_ * 4);
  unsigned short* HB    = (unsigned short*)take((size_t)4096 * I_ * 2);
  int*   counts   = (int*)take(64);
  int*   offsets  = (int*)take(64);
  int*   top_i    = (int*)take((size_t)T_ * 4 * 4);
  float* top_w    = (float*)take((size_t)T_ * 4 * 4);
  int*   perm     = (int*)take((size_t)4096 * 4);
  int*   slot_of  = (int*)take((size_t)4096 * 4);
  float* gate_sig = (float*)take((size_t)T_ * 4);
  int*   gu_tiles = (int*)take((size_t)2048 * 4);
  int*   dn_tiles = (int*)take((size_t)2048 * 4);
  int*   ntl      = (int*)take(64);

  // router (1024 blocks) + all weight transposes (7680 blocks) in one launch
  k_pre<<<8704, 256, 0, stream>>>(x, wrt, wshg, wg, wu, wd, wsg, wsu, wsd,
                                  XB, logits_out, top_i, top_w, gate_sig,
                                  WGUT, WDT, WSGUT, WSDT);
  k_build<<<1, 256, 0, stream>>>(top_i, counts, offsets, perm, slot_of,
                                 gu_tiles, dn_tiles, ntl);

  // worklist-driven compact grids: every block is live work
  k_gemm_gu<<<1024, 256, 0, stream>>>(XB, WSGUT, WGUT, HSB, HB,
                                      counts, offsets, perm, gu_tiles, ntl);
  k_gemm_dn<<<1280, 256, 0, stream>>>(HSB, WSDT, SHOUT, HB, WDT, YD,
                                      counts, offsets, dn_tiles, ntl);
  k_combine<<<T_, 256, 0, stream>>>(YD, SHOUT, gate_sig, top_w, slot_of, out);
}